// Round 8
// baseline (3256.615 us; speedup 1.0000x reference)
//
#include <hip/hip_runtime.h>
#include <stdint.h>

typedef __attribute__((ext_vector_type(8))) short short8;
typedef __attribute__((ext_vector_type(4))) float f32x4;

#define DEV static __device__ __forceinline__

#define L2E 1.4426950408889634f

// ---------------- helpers ----------------
DEV unsigned short f2bf(float f){
  unsigned int u = __float_as_uint(f);
  u = (u + 0x7FFFu + ((u >> 16) & 1u)) >> 16;
  return (unsigned short)u;
}
DEV float bf2f(unsigned short u){
  return __uint_as_float(((unsigned int)u) << 16);
}
DEV float frcp(float x){ return __builtin_amdgcn_rcpf(x); }
// unpack bf16 half c (0=lo,1=hi) of a dword to float
DEV float bfu(unsigned int u, int c){
  return c ? __uint_as_float(u & 0xFFFF0000u) : __uint_as_float(u << 16);
}
// pack two f32 -> 2xbf16 dword (RNE), single instruction
DEV unsigned int cvtpk(float lo, float hi){
  unsigned int r;
  asm("v_cvt_pk_bf16_f32 %0, %1, %2" : "=v"(r) : "v"(lo), "v"(hi));
  return r;
}
DEV float wredsum(float v){
  #pragma unroll
  for (int m = 32; m; m >>= 1) v += __shfl_xor(v, m);
  return v;
}
DEV float wredmax(float v){
  #pragma unroll
  for (int m = 32; m; m >>= 1) v = fmaxf(v, __shfl_xor(v, m));
  return v;
}

// dims
#define BB 64
#define NN 512
#define HH 512
#define HC 256

// physical h-permutation: logical j = blk*32 + c*16 + col  <->  physical p = blk*32 + col*2 + c
DEV int jmap(int p){  // physical -> logical
  return (p & ~31) + (p & 1)*16 + ((p & 31) >> 1);
}

// ---------------- prep: weights -> bf16 (scaled by log2e factors, K-permuted), combined bias ----------------
__global__ void prep_w(const float* __restrict__ wih, const float* __restrict__ whh,
                       const float* __restrict__ bih, const float* __restrict__ bhh,
                       unsigned short* __restrict__ wihb, unsigned short* __restrict__ whhb,
                       float* __restrict__ cbias)
{
  const int NW1 = 2*2*768*512;   // 1572864
  const int NW2 = 2*2*768*256;   // 786432
  const int NCB = 2*1536;        // 3072
  for (int i = blockIdx.x*256 + threadIdx.x; i < NW1+NW2+NCB; i += gridDim.x*256){
    if (i < NW1){
      // wih [2][2][768][512]; layer 1 columns permuted (inputs are physical h)
      const int col = i & 511;
      const int row = (i >> 9) % 768;       // true mod-768
      const int Ld  = i / (768*512);        // L*2+dd
      const int cls = row >> 8;
      const float sc = (cls == 2) ? 2.f*L2E : L2E;
      int scol = col;
      if ((Ld >> 1) == 1){
        const int d2 = col >> 8, p = col & 255;
        scol = d2*256 + jmap(p);
      }
      wihb[i] = f2bf(wih[i - col + scol] * sc);
    } else if (i < NW1+NW2){
      // whh [2][2][768][256]; columns permuted
      const int k = i - NW1;
      const int p = k & 255;
      const int row = (k >> 8) % 768;       // true mod-768
      const int cls = row >> 8;
      const float sc = (cls == 2) ? 2.f*L2E : L2E;
      whhb[k] = f2bf(whh[k - p + jmap(p)] * sc);
    } else {
      int k = i - NW1 - NW2;
      int L = k / 1536, r = k % 1536;
      int dd = r / 768, g = r % 768;
      int idx = (L*2 + dd)*768 + g;
      const float sc = (g >= 512) ? 2.f*L2E : L2E;
      // fold b_ih always; fold b_hh for r,z gates. b_hh[n] stays in recurrence.
      cbias[k] = (bih[idx] + (g < 512 ? bhh[idx] : 0.f)) * sc;
    }
  }
}

// ---------------- prep: mask x -> bf16 copy ----------------
__global__ void prep_x(const float* __restrict__ x, const int* __restrict__ nnode,
                       unsigned short* __restrict__ xpb)
{
  const int TOT4 = (BB*NN*HH) >> 2;  // 4194304
  for (int i = blockIdx.x*256 + threadIdx.x; i < TOT4; i += gridDim.x*256){
    const int e = i << 2;
    const int b = e >> 18;          // /(512*512)
    const int n = (e >> 9) & 511;
    float4 v = *(const float4*)(x + e);
    if (n >= nnode[b]) { v.x = 0.f; v.y = 0.f; v.z = 0.f; v.w = 0.f; }
    ushort4 o;
    o.x = f2bf(v.x); o.y = f2bf(v.y); o.z = f2bf(v.z); o.w = f2bf(v.w);
    *(ushort4*)(xpb + e) = o;
  }
}

// ---------------- input-gate GEMM: C[32768][1536] = A[32768][512] * W[1536][512]^T + cbias ----------------
// Output row layout is GATE-PERMUTED for gru_rec:
//   for n = dir*768 + g, g = cls*256 + j (cls=r/z/n, j = logical hidden idx):
//   newoff = dir*768 + (j>>5)*96 + (j&15)*6 + cls*2 + ((j>>4)&1)
__global__ __launch_bounds__(256, 2) void gemm_xg(
    const unsigned short* __restrict__ A,
    const unsigned short* __restrict__ W,
    const float* __restrict__ cbias,
    unsigned short* __restrict__ C)
{
  const int tid = threadIdx.x;
  const int l = tid & 63, wv = tid >> 6;
  const int col = l & 15, lq = l >> 4;
  const int n0 = blockIdx.x * 128;   // 12 n-tiles
  const int m0 = blockIdx.y * 128;   // 256 m-tiles
  const int wm = wv >> 1, wn = wv & 1;
  __shared__ char As[16384];   // [128 rows][64 k] bf16, 16B-slot XOR swizzle
  __shared__ char Ws[16384];

  f32x4 acc[4][4];
  #pragma unroll
  for (int a = 0; a < 4; a++)
    #pragma unroll
    for (int b2 = 0; b2 < 4; b2++) acc[a][b2] = (f32x4){0.f,0.f,0.f,0.f};

  short8 pa[4], pw[4];
  #pragma unroll
  for (int p = 0; p < 4; p++){
    const int qq = p*256 + tid, row = qq >> 3, sl = qq & 7;
    pa[p] = *(const short8*)(A + (m0+row)*512 + sl*8);
    pw[p] = *(const short8*)(W + (n0+row)*512 + sl*8);
  }

  for (int ko = 0; ko < 8; ++ko){
    __syncthreads();
    #pragma unroll
    for (int p = 0; p < 4; p++){
      const int qq = p*256 + tid, row = qq >> 3, sl = qq & 7;
      *(short8*)(As + row*128 + ((sl ^ (row & 7)) << 4)) = pa[p];
      *(short8*)(Ws + row*128 + ((sl ^ (row & 7)) << 4)) = pw[p];
    }
    __syncthreads();
    if (ko < 7){
      #pragma unroll
      for (int p = 0; p < 4; p++){
        const int qq = p*256 + tid, row = qq >> 3, sl = qq & 7;
        pa[p] = *(const short8*)(A + (m0+row)*512 + (ko+1)*64 + sl*8);
        pw[p] = *(const short8*)(W + (n0+row)*512 + (ko+1)*64 + sl*8);
      }
    }
    #pragma unroll
    for (int kt = 0; kt < 2; kt++){
      short8 af[4], bfr[4];
      #pragma unroll
      for (int mi = 0; mi < 4; mi++){
        const int r = wm*64 + mi*16 + col;
        af[mi] = *(const short8*)(As + r*128 + ((((kt<<2)|lq) ^ (r & 7)) << 4));
      }
      #pragma unroll
      for (int ni = 0; ni < 4; ni++){
        const int r = wn*64 + ni*16 + col;
        bfr[ni] = *(const short8*)(Ws + r*128 + ((((kt<<2)|lq) ^ (r & 7)) << 4));
      }
      #pragma unroll
      for (int mi = 0; mi < 4; mi++)
        #pragma unroll
        for (int ni = 0; ni < 4; ni++)
          acc[mi][ni] = __builtin_amdgcn_mfma_f32_16x16x32_bf16(af[mi], bfr[ni], acc[mi][ni], 0, 0, 0);
    }
  }
  // epilogue: C[m][perm(n)] = bf16(acc + cbias[n])
  #pragma unroll
  for (int ni = 0; ni < 4; ni++){
    const int n = n0 + wn*64 + ni*16 + col;
    const int dirn = (n >= 768) ? 1 : 0;
    const int g = n - dirn*768;
    const int cls = g >> 8;
    const int j = g & 255;
    const int noff = dirn*768 + (j >> 5)*96 + (j & 15)*6 + cls*2 + ((j >> 4) & 1);
    const float cb = cbias[n];
    #pragma unroll
    for (int mi = 0; mi < 4; mi++){
      const int m = m0 + wm*64 + mi*16 + lq*4;
      #pragma unroll
      for (int rg = 0; rg < 4; rg++)
        C[(m + rg)*1536 + noff] = f2bf(acc[mi][ni][rg] + cb);
    }
  }
}

// ---------------- GRU recurrence (v6: packed h, exp2 gates, step-local loads) ----------------
// grid = 8 blocks: dir*4+btile (16 batches each), 512 threads (8 waves).
// Wave w gate-tiles: r:{2w,2w+1} z:{16+2w,16+2w+1} n:{32+2w,32+2w+1} (logical j = 32w + c*16 + col).
// h stored PHYSICALLY as p = 32w + col*2 + c (pairs packed in one dword).
// 5 tiles in VGPRs, 6th in per-wave LDS. hbuf double-buffered (single barrier/step).
// xg loads are STEP-LOCAL (issued at step top, consumed after MFMA block) — no
// persistent prefetch registers (R7's always-live pfA/pfB saturated the unified
// RF: 2 waves/SIMD x (128 VGPR + 128 AGPR) = full 512-reg pool; +24 live regs
// forced shuffling that cost ~580 VALU cy/step).
#define GRU_STEP(HB_R, HB_W, TCUR) do {                                         \
  unsigned int pf[12];                                                          \
  _Pragma("unroll")                                                             \
  for (int rg = 0; rg < 4; rg++){                                               \
    const uint3 v = *(const uint3*)(xg + xgo[rg] + (TCUR)*1536);                \
    pf[rg*3+0] = v.x; pf[rg*3+1] = v.y; pf[rg*3+2] = v.z;                       \
  }                                                                             \
  f32x4 acc[6];                                                                 \
  _Pragma("unroll")                                                             \
  for (int i = 0; i < 6; i++) acc[i] = (f32x4){0.f,0.f,0.f,0.f};                \
  _Pragma("unroll")                                                             \
  for (int kt = 0; kt < 8; kt++){                                               \
    const short8 a = *(const short8*)((HB_R) + rdo[kt]);                        \
    _Pragma("unroll")                                                           \
    for (int i = 0; i < 5; i++)                                                 \
      acc[i] = __builtin_amdgcn_mfma_f32_16x16x32_bf16(a, bw[i][kt], acc[i], 0, 0, 0); \
    const short8 w5 = *(const short8*)(wlds[w] + kt*1024 + l*16);               \
    acc[5] = __builtin_amdgcn_mfma_f32_16x16x32_bf16(a, w5, acc[5], 0, 0, 0);   \
  }                                                                             \
  _Pragma("unroll")                                                             \
  for (int rg = 0; rg < 4; rg++){                                               \
    const unsigned int d0 = pf[rg*3+0], d1 = pf[rg*3+1], d2 = pf[rg*3+2];       \
    const float r0 = frcp(1.f + exp2f(-(bfu(d0,0) + acc[0][rg])));              \
    const float r1 = frcp(1.f + exp2f(-(bfu(d0,1) + acc[1][rg])));              \
    const float z0 = frcp(1.f + exp2f(-(bfu(d1,0) + acc[2][rg])));              \
    const float z1 = frcp(1.f + exp2f(-(bfu(d1,1) + acc[3][rg])));              \
    const float tt0 = bfu(d2,0) + r0*(acc[4][rg] + bhn0);                       \
    const float tt1 = bfu(d2,1) + r1*(acc[5][rg] + bhn1);                       \
    const float n0 = 1.f - 2.f*frcp(1.f + exp2f(tt0));                          \
    const float n1 = 1.f - 2.f*frcp(1.f + exp2f(tt1));                          \
    const float h0 = n0 + z0*(hreg[rg*2+0] - n0);                               \
    const float h1 = n1 + z1*(hreg[rg*2+1] - n1);                               \
    hreg[rg*2+0] = h0; hreg[rg*2+1] = h1;                                       \
    const unsigned int pk = cvtpk(h0, h1);                                      \
    *(unsigned int*)(outb + obo[rg] + (TCUR)*512) = pk;                         \
    *(unsigned int*)((HB_W) + hwo[rg]) = pk;                                    \
  }                                                                             \
  __syncthreads();                                                              \
} while(0)

__global__ __launch_bounds__(512, 2) void gru_rec(
    const unsigned short* __restrict__ xg,  // [64][512][1536] bf16, gate-permuted rows
    const unsigned short* __restrict__ whhL,// [2][768][256] bf16 (this layer, K-permuted, scaled)
    const float* __restrict__ bhhL,         // [2][768] (this layer, raw)
    unsigned short* __restrict__ outb)      // [64][512][512] bf16, physical h layout
{
  const int tid = threadIdx.x;
  const int l = tid & 63, w = tid >> 6;       // 8 waves
  const int col = l & 15, lq = l >> 4;
  const int dir = blockIdx.x >> 2, bt = blockIdx.x & 3;

  __shared__ char hbuf0[8192];     // h bf16 [16 rows][256 phys], XOR-swizzled 16B slots
  __shared__ char hbuf1[8192];
  __shared__ char wlds[8][8192];   // per-wave: 6th tile, 8 kt-frags x 1KB

  const unsigned short* whh_d = whhL + dir*768*256;

  short8 bw[5][8];
  #pragma unroll
  for (int i = 0; i < 6; i++){
    const int nt = (i < 2) ? (2*w + i) : (i < 4) ? (16 + 2*w + (i-2)) : (32 + 2*w + (i-4));
    const int g = nt*16 + col;
    #pragma unroll
    for (int kt = 0; kt < 8; kt++){
      short8 v = *(const short8*)(whh_d + g*256 + kt*32 + lq*8);
      if (i < 5) bw[i][kt] = v;
      else *(short8*)(wlds[w] + kt*1024 + l*16) = v;
    }
  }

  const float bhn0 = bhhL[dir*768 + 512 + 32*w + col] * (2.f*L2E);
  const float bhn1 = bhhL[dir*768 + 512 + 32*w + 16 + col] * (2.f*L2E);

  for (int z = tid; z < 2048; z += 512){
    ((unsigned int*)hbuf0)[z] = 0u;
    ((unsigned int*)hbuf1)[z] = 0u;
  }

  float hreg[8];
  #pragma unroll
  for (int i = 0; i < 8; i++) hreg[i] = 0.f;

  int xgo[4], obo[4], hwo[4], rdo[8];
  #pragma unroll
  for (int rg = 0; rg < 4; rg++){
    const int bg = bt*16 + lq*4 + rg;
    xgo[rg] = bg*(512*1536) + dir*768 + (w*16 + col)*6;
    obo[rg] = bg*(512*512) + dir*256 + (32*w + col*2);
    const int brow = lq*4 + rg;
    hwo[rg] = brow*512 + ((((w*4 + (col>>2)) ^ (brow & 7)) << 4) | ((col & 3) << 2));
  }
  #pragma unroll
  for (int kt = 0; kt < 8; kt++)
    rdo[kt] = col*512 + (((kt*4 + lq) ^ (col & 7)) << 4);

  __syncthreads();

  const int t0 = dir ? 511 : 0;
  const int dstep = dir ? -1 : 1;
  int tc = t0;
  #pragma unroll 1
  for (int ss = 0; ss < 256; ss++){
    const int tA = tc;
    const int tB = tA + dstep;
    GRU_STEP(hbuf0, hbuf1, tA);
    GRU_STEP(hbuf1, hbuf0, tB);
    tc = tB + dstep;
  }
}

// ---------------- residual + LayerNorm + raw attention score ----------------
// grid = B*N blocks of 64 threads. Thread l owns LOGICAL h-indices l*8..l*8+7; gathers physical h2b.
__global__ void ln_score(
    const unsigned short* __restrict__ h2b, const float* __restrict__ x,
    const int* __restrict__ nnode,
    const float* __restrict__ gam, const float* __restrict__ bet,
    const float* __restrict__ watt,
    float* __restrict__ hln, float* __restrict__ scores)
{
  const int bidx = blockIdx.x;
  const int b = bidx >> 9, n = bidx & 511;
  const int l = threadIdx.x;
  const int base = bidx*512;
  const int j0 = l*8;                 // logical
  const bool valid = n < nnode[b];

  // physical gather: logical j = blk*32 + c*16 + col -> phys = blk*32 + col*2 + c
  const int d2 = j0 >> 8;
  const int jj = j0 & 255;
  const int p0 = (jj & ~31) + (jj & 15)*2;
  const int cs = (jj >> 4) & 1;
  const uint4 ua = *(const uint4*)(h2b + base + d2*256 + p0);
  const uint4 ub = *(const uint4*)(h2b + base + d2*256 + p0 + 8);
  float hv[8];
  hv[0] = bfu(ua.x, cs); hv[1] = bfu(ua.y, cs); hv[2] = bfu(ua.z, cs); hv[3] = bfu(ua.w, cs);
  hv[4] = bfu(ub.x, cs); hv[5] = bfu(ub.y, cs); hv[6] = bfu(ub.z, cs); hv[7] = bfu(ub.w, cs);

  float y[8];
  #pragma unroll
  for (int p = 0; p < 2; p++){
    float4 xv = (float4){0.f,0.f,0.f,0.f};
    if (valid) xv = *(const float4*)(x + base + j0 + p*4);
    y[p*4+0] = hv[p*4+0] + xv.x;
    y[p*4+1] = hv[p*4+1] + xv.y;
    y[p*4+2] = hv[p*4+2] + xv.z;
    y[p*4+3] = hv[p*4+3] + xv.w;
  }
  float s = 0.f, sq = 0.f;
  #pragma unroll
  for (int i = 0; i < 8; i++){ s += y[i]; sq += y[i]*y[i]; }
  s = wredsum(s); sq = wredsum(sq);
  const float mu = s * (1.f/512.f);
  const float rstd = rsqrtf(sq * (1.f/512.f) - mu*mu + 1e-5f);

  float dot = 0.f;
  #pragma unroll
  for (int p = 0; p < 2; p++){
    const float4 gv = *(const float4*)(gam + j0 + p*4);
    const float4 bv = *(const float4*)(bet + j0 + p*4);
    const float4 wv = *(const float4*)(watt + j0 + p*4);
    float4 o;
    o.x = (y[p*4+0] - mu)*rstd*gv.x + bv.x;
    o.y = (y[p*4+1] - mu)*rstd*gv.y + bv.y;
    o.z = (y[p*4+2] - mu)*rstd*gv.z + bv.z;
    o.w = (y[p*4+3] - mu)*rstd*gv.w + bv.w;
    dot += o.x*wv.x + o.y*wv.y + o.z*wv.z + o.w*wv.w;
    *(float4*)(hln + base + j0 + p*4) = o;
  }
  dot = wredsum(dot);
  if (l == 0) scores[bidx] = dot;
}

// ---------------- softmax + weighted pooling ----------------
__global__ void attn_pool(
    const float* __restrict__ hln, const float* __restrict__ scores,
    const float* __restrict__ watt, const float* __restrict__ q,
    float* __restrict__ out)
{
  __shared__ float sc[512];
  __shared__ float red[12];
  const int tid = threadIdx.x, l = tid & 63, w = tid >> 6;
  const int b = blockIdx.x;

  float p = q[b*512 + tid]*watt[512 + tid] + q[b*512 + 256 + tid]*watt[768 + tid];
  p = wredsum(p);
  if (l == 0) red[w] = p;
  __syncthreads();
  const float qd = red[0] + red[1] + red[2] + red[3];

  float s0 = scores[b*512 + tid] + qd;        s0 = s0 > 0.f ? s0 : 0.01f*s0;
  float s1 = scores[b*512 + 256 + tid] + qd;  s1 = s1 > 0.f ? s1 : 0.01f*s1;
  float m_ = wredmax(fmaxf(s0, s1));
  if (l == 0) red[4 + w] = m_;
  __syncthreads();
  const float mx = fmaxf(fmaxf(red[4], red[5]), fmaxf(red[6], red[7]));
  const float e0 = __expf(s0 - mx), e1 = __expf(s1 - mx);
  sc[tid] = e0; sc[tid + 256] = e1;
  float ss = wredsum(e0 + e1);
  if (l == 0) red[8 + w] = ss;
  __syncthreads();
  const float rden = 1.f / (red[8] + red[9] + red[10] + red[11]);

  const int h0 = tid*2;
  float a0 = 0.f, a1 = 0.f;
  for (int t = 0; t < 512; t++){
    const float wv = sc[t];
    const float2 v = *(const float2*)(hln + (b*512 + t)*512 + h0);
    a0 += v.x*wv; a1 += v.y*wv;
  }
  out[b*512 + h0]     = a0 * rden;
  out[b*512 + h0 + 1] = a1 * rden;
}

// ---------------- launcher ----------------
extern "C" void kernel_launch(void* const* d_in, const int* in_sizes, int n_in,
                              void* d_out, int out_size, void* d_ws, size_t ws_size,
                              hipStream_t stream)
{
  (void)in_sizes; (void)n_in; (void)out_size; (void)ws_size;
  const float* x    = (const float*)d_in[0];
  const int*   nn   = (const int*)d_in[1];
  const float* wih  = (const float*)d_in[2];
  const float* whh  = (const float*)d_in[3];
  const float* bih  = (const float*)d_in[4];
  const float* bhh  = (const float*)d_in[5];
  const float* lg   = (const float*)d_in[6];
  const float* lb   = (const float*)d_in[7];
  const float* watt = (const float*)d_in[8];
  const float* q    = (const float*)d_in[9];
  float* out = (float*)d_out;

  // workspace layout (total ~197 MiB)
  char* ws = (char*)d_ws;
  unsigned short* xg_b = (unsigned short*)(ws + 0);           // 100663296 B  [64][512][1536] bf16 (gate-permuted)
  unsigned short* xp_b = (unsigned short*)(ws + 100663296);   // 33554432 B
  unsigned short* h1_b = (unsigned short*)(ws + 134217728);   // 33554432 B
  unsigned short* h2_b = (unsigned short*)(ws + 167772160);   // 33554432 B
  unsigned short* wihb = (unsigned short*)(ws + 201326592);   // 3145728 B
  unsigned short* whhb = (unsigned short*)(ws + 204472320);   // 1572864 B
  float*         cbias = (float*)(ws + 206045184);            // 12288 B
  float*        scores = (float*)(ws + 206057472);            // 131072 B
  float*           hln = (float*)(ws + 0);                    // 67108864 B, reuses xg region

  prep_w<<<dim3(1024), dim3(256), 0, stream>>>(wih, whh, bih, bhh, wihb, whhb, cbias);
  prep_x<<<dim3(2048), dim3(256), 0, stream>>>(x, nn, xp_b);

  // layer 0
  gemm_xg<<<dim3(12, 256), dim3(256), 0, stream>>>(xp_b, wihb, cbias, xg_b);
  gru_rec<<<dim3(8), dim3(512), 0, stream>>>(xg_b, whhb, bhh, h1_b);

  // layer 1
  gemm_xg<<<dim3(12, 256), dim3(256), 0, stream>>>(h1_b, wihb + 1536*512, cbias + 1536, xg_b);
  gru_rec<<<dim3(8), dim3(512), 0, stream>>>(xg_b, whhb + 2*768*256, bhh + 1536, h2_b);

  ln_score<<<dim3(64*512), dim3(64), 0, stream>>>(h2_b, x, nn, lg, lb, watt, hln, scores);
  attn_pool<<<dim3(64), dim3(256), 0, stream>>>(hln, scores, watt, q, out);
}

// Round 9
// 2259.076 us; speedup vs baseline: 1.4416x; 1.4416x over previous
//
#include <hip/hip_runtime.h>
#include <stdint.h>

typedef __attribute__((ext_vector_type(8))) short short8;
typedef __attribute__((ext_vector_type(4))) float f32x4;

#define DEV static __device__ __forceinline__

#define L2E 1.4426950408889634f

// ---------------- helpers ----------------
DEV unsigned short f2bf(float f){
  unsigned int u = __float_as_uint(f);
  u = (u + 0x7FFFu + ((u >> 16) & 1u)) >> 16;
  return (unsigned short)u;
}
DEV float bf2f(unsigned short u){
  return __uint_as_float(((unsigned int)u) << 16);
}
DEV float frcp(float x){ return __builtin_amdgcn_rcpf(x); }
// raw v_exp_f32 (2^x). Numerically proven identical to exp2f on-chip (R5 == R6 bitwise).
DEV float exp2a(float x){ float r; asm("v_exp_f32 %0, %1" : "=v"(r) : "v"(x)); return r; }
// unpack bf16 half c (0=lo,1=hi) of a dword to float
DEV float bfu(unsigned int u, int c){
  return c ? __uint_as_float(u & 0xFFFF0000u) : __uint_as_float(u << 16);
}
DEV float wredsum(float v){
  #pragma unroll
  for (int m = 32; m; m >>= 1) v += __shfl_xor(v, m);
  return v;
}
DEV float wredmax(float v){
  #pragma unroll
  for (int m = 32; m; m >>= 1) v = fmaxf(v, __shfl_xor(v, m));
  return v;
}

// dims
#define BB 64
#define NN 512
#define HH 512
#define HC 256

// ---------------- prep: weights -> bf16 (rows scaled by L2E / 2*L2E), combined bias ----------------
// NO layout permutes (h stays logical). Scaling folds log2e into the exponent so gates
// use raw v_exp_f32 without per-gate multiplies.
__global__ void prep_w(const float* __restrict__ wih, const float* __restrict__ whh,
                       const float* __restrict__ bih, const float* __restrict__ bhh,
                       unsigned short* __restrict__ wihb, unsigned short* __restrict__ whhb,
                       float* __restrict__ cbias)
{
  const int NW1 = 2*2*768*512;   // 1572864
  const int NW2 = 2*2*768*256;   // 786432
  const int NCB = 2*1536;        // 3072
  for (int i = blockIdx.x*256 + threadIdx.x; i < NW1+NW2+NCB; i += gridDim.x*256){
    if (i < NW1){
      const int row = (i >> 9) % 768;       // true mod-768
      const float sc = ((row >> 8) == 2) ? 2.f*L2E : L2E;
      wihb[i] = f2bf(wih[i] * sc);
    } else if (i < NW1+NW2){
      const int k = i - NW1;
      const int row = (k >> 8) % 768;       // true mod-768
      const float sc = ((row >> 8) == 2) ? 2.f*L2E : L2E;
      whhb[k] = f2bf(whh[k] * sc);
    } else {
      int k = i - NW1 - NW2;
      int L = k / 1536, r = k % 1536;
      int dd = r / 768, g = r % 768;
      int idx = (L*2 + dd)*768 + g;
      const float sc = (g >= 512) ? 2.f*L2E : L2E;
      // fold b_ih always; fold b_hh for r,z gates. b_hh[n] stays in recurrence.
      cbias[k] = (bih[idx] + (g < 512 ? bhh[idx] : 0.f)) * sc;
    }
  }
}

// ---------------- prep: mask x -> bf16 copy ----------------
__global__ void prep_x(const float* __restrict__ x, const int* __restrict__ nnode,
                       unsigned short* __restrict__ xpb)
{
  const int TOT4 = (BB*NN*HH) >> 2;  // 4194304
  for (int i = blockIdx.x*256 + threadIdx.x; i < TOT4; i += gridDim.x*256){
    const int e = i << 2;
    const int b = e >> 18;          // /(512*512)
    const int n = (e >> 9) & 511;
    float4 v = *(const float4*)(x + e);
    if (n >= nnode[b]) { v.x = 0.f; v.y = 0.f; v.z = 0.f; v.w = 0.f; }
    ushort4 o;
    o.x = f2bf(v.x); o.y = f2bf(v.y); o.z = f2bf(v.z); o.w = f2bf(v.w);
    *(ushort4*)(xpb + e) = o;
  }
}

// ---------------- input-gate GEMM: C[32768][1536] = A[32768][512] * W[1536][512]^T + cbias ----------------
// Output row layout is GATE-PERMUTED for gru_rec:
//   for n = dir*768 + g, g = cls*256 + j (cls=r/z/n, j = hidden idx in [0,256)):
//   newoff = dir*768 + (j>>5)*96 + (j&15)*6 + cls*2 + ((j>>4)&1)
__global__ __launch_bounds__(256, 2) void gemm_xg(
    const unsigned short* __restrict__ A,
    const unsigned short* __restrict__ W,
    const float* __restrict__ cbias,
    unsigned short* __restrict__ C)
{
  const int tid = threadIdx.x;
  const int l = tid & 63, wv = tid >> 6;
  const int col = l & 15, lq = l >> 4;
  const int n0 = blockIdx.x * 128;   // 12 n-tiles
  const int m0 = blockIdx.y * 128;   // 256 m-tiles
  const int wm = wv >> 1, wn = wv & 1;
  __shared__ char As[16384];   // [128 rows][64 k] bf16, 16B-slot XOR swizzle
  __shared__ char Ws[16384];

  f32x4 acc[4][4];
  #pragma unroll
  for (int a = 0; a < 4; a++)
    #pragma unroll
    for (int b2 = 0; b2 < 4; b2++) acc[a][b2] = (f32x4){0.f,0.f,0.f,0.f};

  short8 pa[4], pw[4];
  #pragma unroll
  for (int p = 0; p < 4; p++){
    const int qq = p*256 + tid, row = qq >> 3, sl = qq & 7;
    pa[p] = *(const short8*)(A + (m0+row)*512 + sl*8);
    pw[p] = *(const short8*)(W + (n0+row)*512 + sl*8);
  }

  for (int ko = 0; ko < 8; ++ko){
    __syncthreads();
    #pragma unroll
    for (int p = 0; p < 4; p++){
      const int qq = p*256 + tid, row = qq >> 3, sl = qq & 7;
      *(short8*)(As + row*128 + ((sl ^ (row & 7)) << 4)) = pa[p];
      *(short8*)(Ws + row*128 + ((sl ^ (row & 7)) << 4)) = pw[p];
    }
    __syncthreads();
    if (ko < 7){
      #pragma unroll
      for (int p = 0; p < 4; p++){
        const int qq = p*256 + tid, row = qq >> 3, sl = qq & 7;
        pa[p] = *(const short8*)(A + (m0+row)*512 + (ko+1)*64 + sl*8);
        pw[p] = *(const short8*)(W + (n0+row)*512 + (ko+1)*64 + sl*8);
      }
    }
    #pragma unroll
    for (int kt = 0; kt < 2; kt++){
      short8 af[4], bfr[4];
      #pragma unroll
      for (int mi = 0; mi < 4; mi++){
        const int r = wm*64 + mi*16 + col;
        af[mi] = *(const short8*)(As + r*128 + ((((kt<<2)|lq) ^ (r & 7)) << 4));
      }
      #pragma unroll
      for (int ni = 0; ni < 4; ni++){
        const int r = wn*64 + ni*16 + col;
        bfr[ni] = *(const short8*)(Ws + r*128 + ((((kt<<2)|lq) ^ (r & 7)) << 4));
      }
      #pragma unroll
      for (int mi = 0; mi < 4; mi++)
        #pragma unroll
        for (int ni = 0; ni < 4; ni++)
          acc[mi][ni] = __builtin_amdgcn_mfma_f32_16x16x32_bf16(af[mi], bfr[ni], acc[mi][ni], 0, 0, 0);
    }
  }
  // epilogue: C[m][perm(n)] = bf16(acc + cbias[n])
  #pragma unroll
  for (int ni = 0; ni < 4; ni++){
    const int n = n0 + wn*64 + ni*16 + col;
    const int dirn = (n >= 768) ? 1 : 0;
    const int g = n - dirn*768;
    const int cls = g >> 8;
    const int j = g & 255;
    const int noff = dirn*768 + (j >> 5)*96 + (j & 15)*6 + cls*2 + ((j >> 4) & 1);
    const float cb = cbias[n];
    #pragma unroll
    for (int mi = 0; mi < 4; mi++){
      const int m = m0 + wm*64 + mi*16 + lq*4;
      #pragma unroll
      for (int rg = 0; rg < 4; rg++)
        C[(m + rg)*1536 + noff] = f2bf(acc[mi][ni][rg] + cb);
    }
  }
}

// ---------------- GRU recurrence (v7 = R4 skeleton + prescaled exp2 gates) ----------------
// grid = 8 blocks: dir*4+btile (16 batches each), 512 threads (8 waves).
// Wave w gate-tiles: r:{2w,2w+1} z:{16+2w,16+2w+1} n:{32+2w,32+2w+1} (j = 32w + c*16 + col).
// 5 tiles in VGPRs (bw[5][8]), 6th in per-wave LDS. hbuf double-buffered (1 barrier/step).
// xg prefetched ONE STEP AHEAD via static pfA/pfB register sets (load-bearing: removing
// it cost +1240 idle cy/step in R8). Gate preacts pre-scaled by L2E (r,z) / 2*L2E (n),
// so gates are: sigma = rcp(1+exp2(-x)), tanh = 1-2*rcp(1+exp2(x)) — raw v_exp_f32.
#define GRU_STEP(HB_R, HB_W, PF_CUR, PF_NXT, TCUR, TNEXT) do {                  \
  _Pragma("unroll")                                                             \
  for (int rg = 0; rg < 4; rg++){                                               \
    const unsigned int* pp = (const unsigned int*)(xg + xgo[rg] + (TNEXT)*1536);\
    PF_NXT[rg*3+0] = pp[0]; PF_NXT[rg*3+1] = pp[1]; PF_NXT[rg*3+2] = pp[2];     \
  }                                                                             \
  f32x4 acc[6];                                                                 \
  _Pragma("unroll")                                                             \
  for (int i = 0; i < 6; i++) acc[i] = (f32x4){0.f,0.f,0.f,0.f};                \
  _Pragma("unroll")                                                             \
  for (int kt = 0; kt < 8; kt++){                                               \
    const short8 a = *(const short8*)((HB_R) + col*512 + (((kt*4 + lq) ^ (col & 7)) << 4)); \
    _Pragma("unroll")                                                           \
    for (int i = 0; i < 5; i++)                                                 \
      acc[i] = __builtin_amdgcn_mfma_f32_16x16x32_bf16(a, bw[i][kt], acc[i], 0, 0, 0); \
    const short8 w5 = *(const short8*)(wlds[w] + kt*1024 + l*16);               \
    acc[5] = __builtin_amdgcn_mfma_f32_16x16x32_bf16(a, w5, acc[5], 0, 0, 0);   \
  }                                                                             \
  _Pragma("unroll")                                                             \
  for (int c = 0; c < 2; c++){                                                  \
    const int j = 32*w + c*16 + col;                                            \
    _Pragma("unroll")                                                           \
    for (int rg = 0; rg < 4; rg++){                                             \
      const float xr = bfu(PF_CUR[rg*3+0], c);                                  \
      const float xz = bfu(PF_CUR[rg*3+1], c);                                  \
      const float xn = bfu(PF_CUR[rg*3+2], c);                                  \
      const float r_ = frcp(1.f + exp2a(-(xr + acc[c][rg])));                   \
      const float z_ = frcp(1.f + exp2a(-(xz + acc[2+c][rg])));                 \
      const float tt = xn + r_*(acc[4+c][rg] + bhn[c]);                         \
      const float n_ = 1.f - 2.f*frcp(1.f + exp2a(tt));                         \
      const float h0 = hreg[c*4 + rg];                                          \
      const float hn2 = n_ + z_*(h0 - n_);                                      \
      hreg[c*4 + rg] = hn2;                                                     \
      const unsigned short hb = f2bf(hn2);                                      \
      outb[obo[rg] + (TCUR)*512 + c*16] = hb;                                   \
      const int brow = lq*4 + rg;                                               \
      *(unsigned short*)((HB_W) + brow*512 + ((((j >> 3) ^ (brow & 7)) << 4) | ((j & 7) << 1))) = hb; \
    }                                                                           \
  }                                                                             \
  __syncthreads();                                                              \
} while(0)

__global__ __launch_bounds__(512, 2) void gru_rec(
    const unsigned short* __restrict__ xg,  // [64][512][1536] bf16, gate-permuted rows (prescaled)
    const unsigned short* __restrict__ whhL,// [2][768][256] bf16 (this layer, row-scaled)
    const float* __restrict__ bhhL,         // [2][768] (this layer, raw)
    unsigned short* __restrict__ outb)      // [64][512][512] bf16, logical h layout
{
  const int tid = threadIdx.x;
  const int l = tid & 63, w = tid >> 6;       // 8 waves
  const int col = l & 15, lq = l >> 4;
  const int dir = blockIdx.x >> 2, bt = blockIdx.x & 3;

  __shared__ char hbuf0[8192];     // h bf16 [16 b][256 j], XOR-swizzled 16B slots
  __shared__ char hbuf1[8192];
  __shared__ char wlds[8][8192];   // per-wave: 6th tile, 8 kt-frags x 1KB

  const unsigned short* whh_d = whhL + dir*768*256;

  // weight fragments: B-frag lane holds W[g = nt*16 + col][k = kt*32 + lq*8 .. +8]
  short8 bw[5][8];
  #pragma unroll
  for (int i = 0; i < 6; i++){
    const int nt = (i < 2) ? (2*w + i) : (i < 4) ? (16 + 2*w + (i-2)) : (32 + 2*w + (i-4));
    const int g = nt*16 + col;
    #pragma unroll
    for (int kt = 0; kt < 8; kt++){
      short8 v = *(const short8*)(whh_d + g*256 + kt*32 + lq*8);
      if (i < 5) bw[i][kt] = v;
      else *(short8*)(wlds[w] + kt*1024 + l*16) = v;
    }
  }

  float bhn[2];
  bhn[0] = bhhL[dir*768 + 512 + 32*w + col] * (2.f*L2E);
  bhn[1] = bhhL[dir*768 + 512 + 32*w + 16 + col] * (2.f*L2E);

  for (int z = tid; z < 2048; z += 512){
    ((unsigned int*)hbuf0)[z] = 0u;
    ((unsigned int*)hbuf1)[z] = 0u;
  }

  float hreg[8];
  #pragma unroll
  for (int i = 0; i < 8; i++) hreg[i] = 0.f;

  int xgo[4], obo[4];
  #pragma unroll
  for (int rg = 0; rg < 4; rg++){
    const int bg = bt*16 + lq*4 + rg;
    xgo[rg] = bg*(512*1536) + dir*768 + (w*16 + col)*6;
    obo[rg] = bg*(512*512) + dir*256 + 32*w + col;
  }

  // prologue: prefetch step 0
  unsigned int pfA[12], pfB[12];
  const int t0 = dir ? 511 : 0;
  const int dstep = dir ? -1 : 1;
  #pragma unroll
  for (int rg = 0; rg < 4; rg++){
    const unsigned int* pp = (const unsigned int*)(xg + xgo[rg] + t0*1536);
    pfA[rg*3+0] = pp[0]; pfA[rg*3+1] = pp[1]; pfA[rg*3+2] = pp[2];
  }

  __syncthreads();

  int tc = t0;
  #pragma unroll 1
  for (int ss = 0; ss < 256; ss++){
    const int tA = tc;
    const int tB = tA + dstep;
    const int tC = (ss == 255) ? tB : (tB + dstep);
    GRU_STEP(hbuf0, hbuf1, pfA, pfB, tA, tB);
    GRU_STEP(hbuf1, hbuf0, pfB, pfA, tB, tC);
    tc = tC;
  }
}

// ---------------- residual + LayerNorm + raw attention score ----------------
// grid = B*N blocks of 64 threads (1 wave). blockIdx.x = b*512 + t.
__global__ void ln_score(
    const unsigned short* __restrict__ h2b, const float* __restrict__ x,
    const int* __restrict__ nnode,
    const float* __restrict__ gam, const float* __restrict__ bet,
    const float* __restrict__ watt,
    float* __restrict__ hln, float* __restrict__ scores)
{
  const int bidx = blockIdx.x;
  const int b = bidx >> 9, n = bidx & 511;
  const int l = threadIdx.x;
  const int base = bidx*512;
  const int i0 = l*8;
  const bool valid = n < nnode[b];

  const short8 hv = *(const short8*)(h2b + base + i0);
  float y[8];
  #pragma unroll
  for (int p = 0; p < 2; p++){
    float4 xv = (float4){0.f,0.f,0.f,0.f};
    if (valid) xv = *(const float4*)(x + base + i0 + p*4);
    y[p*4+0] = bf2f((unsigned short)hv[p*4+0]) + xv.x;
    y[p*4+1] = bf2f((unsigned short)hv[p*4+1]) + xv.y;
    y[p*4+2] = bf2f((unsigned short)hv[p*4+2]) + xv.z;
    y[p*4+3] = bf2f((unsigned short)hv[p*4+3]) + xv.w;
  }
  float s = 0.f, sq = 0.f;
  #pragma unroll
  for (int i = 0; i < 8; i++){ s += y[i]; sq += y[i]*y[i]; }
  s = wredsum(s); sq = wredsum(sq);
  const float mu = s * (1.f/512.f);
  const float rstd = rsqrtf(sq * (1.f/512.f) - mu*mu + 1e-5f);

  float dot = 0.f;
  #pragma unroll
  for (int p = 0; p < 2; p++){
    const float4 gv = *(const float4*)(gam + i0 + p*4);
    const float4 bv = *(const float4*)(bet + i0 + p*4);
    const float4 wv = *(const float4*)(watt + i0 + p*4);
    float4 o;
    o.x = (y[p*4+0] - mu)*rstd*gv.x + bv.x;
    o.y = (y[p*4+1] - mu)*rstd*gv.y + bv.y;
    o.z = (y[p*4+2] - mu)*rstd*gv.z + bv.z;
    o.w = (y[p*4+3] - mu)*rstd*gv.w + bv.w;
    dot += o.x*wv.x + o.y*wv.y + o.z*wv.z + o.w*wv.w;
    *(float4*)(hln + base + i0 + p*4) = o;
  }
  dot = wredsum(dot);
  if (l == 0) scores[bidx] = dot;
}

// ---------------- softmax + weighted pooling ----------------
// grid = 64 blocks (one per batch), 256 threads.
__global__ void attn_pool(
    const float* __restrict__ hln, const float* __restrict__ scores,
    const float* __restrict__ watt, const float* __restrict__ q,
    float* __restrict__ out)
{
  __shared__ float sc[512];
  __shared__ float red[12];
  const int tid = threadIdx.x, l = tid & 63, w = tid >> 6;
  const int b = blockIdx.x;

  float p = q[b*512 + tid]*watt[512 + tid] + q[b*512 + 256 + tid]*watt[768 + tid];
  p = wredsum(p);
  if (l == 0) red[w] = p;
  __syncthreads();
  const float qd = red[0] + red[1] + red[2] + red[3];

  float s0 = scores[b*512 + tid] + qd;        s0 = s0 > 0.f ? s0 : 0.01f*s0;
  float s1 = scores[b*512 + 256 + tid] + qd;  s1 = s1 > 0.f ? s1 : 0.01f*s1;
  float m_ = wredmax(fmaxf(s0, s1));
  if (l == 0) red[4 + w] = m_;
  __syncthreads();
  const float mx = fmaxf(fmaxf(red[4], red[5]), fmaxf(red[6], red[7]));
  const float e0 = __expf(s0 - mx), e1 = __expf(s1 - mx);
  sc[tid] = e0; sc[tid + 256] = e1;
  float ss = wredsum(e0 + e1);
  if (l == 0) red[8 + w] = ss;
  __syncthreads();
  const float rden = 1.f / (red[8] + red[9] + red[10] + red[11]);

  const int h0 = tid*2;
  float a0 = 0.f, a1 = 0.f;
  for (int t = 0; t < 512; t++){
    const float wv = sc[t];
    const float2 v = *(const float2*)(hln + (b*512 + t)*512 + h0);
    a0 += v.x*wv; a1 += v.y*wv;
  }
  out[b*512 + h0]     = a0 * rden;
  out[b*512 + h0 + 1] = a1 * rden;
}

// ---------------- launcher ----------------
extern "C" void kernel_launch(void* const* d_in, const int* in_sizes, int n_in,
                              void* d_out, int out_size, void* d_ws, size_t ws_size,
                              hipStream_t stream)
{
  (void)in_sizes; (void)n_in; (void)out_size; (void)ws_size;
  const float* x    = (const float*)d_in[0];
  const int*   nn   = (const int*)d_in[1];
  const float* wih  = (const float*)d_in[2];
  const float* whh  = (const float*)d_in[3];
  const float* bih  = (const float*)d_in[4];
  const float* bhh  = (const float*)d_in[5];
  const float* lg   = (const float*)d_in[6];
  const float* lb   = (const float*)d_in[7];
  const float* watt = (const float*)d_in[8];
  const float* q    = (const float*)d_in[9];
  float* out = (float*)d_out;

  // workspace layout (total ~197 MiB)
  char* ws = (char*)d_ws;
  unsigned short* xg_b = (unsigned short*)(ws + 0);           // 100663296 B  [64][512][1536] bf16 (gate-permuted)
  unsigned short* xp_b = (unsigned short*)(ws + 100663296);   // 33554432 B
  unsigned short* h1_b = (unsigned short*)(ws + 134217728);   // 33554432 B
  unsigned short* h2_b = (unsigned short*)(ws + 167772160);   // 33554432 B
  unsigned short* wihb = (unsigned short*)(ws + 201326592);   // 3145728 B
  unsigned short* whhb = (unsigned short*)(ws + 204472320);   // 1572864 B
  float*         cbias = (float*)(ws + 206045184);            // 12288 B
  float*        scores = (float*)(ws + 206057472);            // 131072 B
  float*           hln = (float*)(ws + 0);                    // 67108864 B, reuses xg region

  prep_w<<<dim3(1024), dim3(256), 0, stream>>>(wih, whh, bih, bhh, wihb, whhb, cbias);
  prep_x<<<dim3(2048), dim3(256), 0, stream>>>(x, nn, xp_b);

  // layer 0
  gemm_xg<<<dim3(12, 256), dim3(256), 0, stream>>>(xp_b, wihb, cbias, xg_b);
  gru_rec<<<dim3(8), dim3(512), 0, stream>>>(xg_b, whhb, bhh, h1_b);

  // layer 1
  gemm_xg<<<dim3(12, 256), dim3(256), 0, stream>>>(h1_b, wihb + 1536*512, cbias + 1536, xg_b);
  gru_rec<<<dim3(8), dim3(512), 0, stream>>>(xg_b, whhb + 2*768*256, bhh + 1536, h2_b);

  ln_score<<<dim3(64*512), dim3(64), 0, stream>>>(h2_b, x, nn, lg, lb, watt, hln, scores);
  attn_pool<<<dim3(64), dim3(256), 0, stream>>>(hln, scores, watt, q, out);
}

// Round 10
// 1549.968 us; speedup vs baseline: 2.1011x; 1.4575x over previous
//
#include <hip/hip_runtime.h>
#include <stdint.h>

typedef __attribute__((ext_vector_type(8))) short short8;
typedef __attribute__((ext_vector_type(4))) float f32x4;

#define DEV static __device__ __forceinline__

#define L2E 1.4426950408889634f

// ---------------- helpers ----------------
DEV unsigned short f2bf(float f){
  unsigned int u = __float_as_uint(f);
  u = (u + 0x7FFFu + ((u >> 16) & 1u)) >> 16;
  return (unsigned short)u;
}
DEV float bf2f(unsigned short u){
  return __uint_as_float(((unsigned int)u) << 16);
}
DEV float frcp(float x){ return __builtin_amdgcn_rcpf(x); }
// raw v_exp_f32 (2^x). Proven identical to exp2f on-chip (R5 == R6 bitwise).
DEV float exp2a(float x){ float r; asm("v_exp_f32 %0, %1" : "=v"(r) : "v"(x)); return r; }
// unpack bf16 half c (0=lo,1=hi) of a dword to float
DEV float bfu(unsigned int u, int c){
  return c ? __uint_as_float(u & 0xFFFF0000u) : __uint_as_float(u << 16);
}
DEV float wredsum(float v){
  #pragma unroll
  for (int m = 32; m; m >>= 1) v += __shfl_xor(v, m);
  return v;
}
DEV float wredmax(float v){
  #pragma unroll
  for (int m = 32; m; m >>= 1) v = fmaxf(v, __shfl_xor(v, m));
  return v;
}

// dims
#define BB 64
#define NN 512
#define HH 512
#define HC 256

// ---------------- prep: weights -> bf16 (rows scaled by L2E / 2*L2E), combined bias ----------------
__global__ void prep_w(const float* __restrict__ wih, const float* __restrict__ whh,
                       const float* __restrict__ bih, const float* __restrict__ bhh,
                       unsigned short* __restrict__ wihb, unsigned short* __restrict__ whhb,
                       float* __restrict__ cbias)
{
  const int NW1 = 2*2*768*512;   // 1572864
  const int NW2 = 2*2*768*256;   // 786432
  const int NCB = 2*1536;        // 3072
  for (int i = blockIdx.x*256 + threadIdx.x; i < NW1+NW2+NCB; i += gridDim.x*256){
    if (i < NW1){
      const int row = (i >> 9) % 768;       // true mod-768
      const float sc = ((row >> 8) == 2) ? 2.f*L2E : L2E;
      wihb[i] = f2bf(wih[i] * sc);
    } else if (i < NW1+NW2){
      const int k = i - NW1;
      const int row = (k >> 8) % 768;       // true mod-768
      const float sc = ((row >> 8) == 2) ? 2.f*L2E : L2E;
      whhb[k] = f2bf(whh[k] * sc);
    } else {
      int k = i - NW1 - NW2;
      int L = k / 1536, r = k % 1536;
      int dd = r / 768, g = r % 768;
      int idx = (L*2 + dd)*768 + g;
      const float sc = (g >= 512) ? 2.f*L2E : L2E;
      // fold b_ih always; fold b_hh for r,z gates. b_hh[n] stays in recurrence.
      cbias[k] = (bih[idx] + (g < 512 ? bhh[idx] : 0.f)) * sc;
    }
  }
}

// ---------------- prep: mask x -> bf16 copy ----------------
__global__ void prep_x(const float* __restrict__ x, const int* __restrict__ nnode,
                       unsigned short* __restrict__ xpb)
{
  const int TOT4 = (BB*NN*HH) >> 2;  // 4194304
  for (int i = blockIdx.x*256 + threadIdx.x; i < TOT4; i += gridDim.x*256){
    const int e = i << 2;
    const int b = e >> 18;          // /(512*512)
    const int n = (e >> 9) & 511;
    float4 v = *(const float4*)(x + e);
    if (n >= nnode[b]) { v.x = 0.f; v.y = 0.f; v.z = 0.f; v.w = 0.f; }
    ushort4 o;
    o.x = f2bf(v.x); o.y = f2bf(v.y); o.z = f2bf(v.z); o.w = f2bf(v.w);
    *(ushort4*)(xpb + e) = o;
  }
}

// ---------------- input-gate GEMM: C[32768][1536] = A[32768][512] * W[1536][512]^T + cbias ----------------
// Output row layout is GATE-PERMUTED for gru_rec:
//   for n = dir*768 + g, g = cls*256 + j (cls=r/z/n, j = hidden idx in [0,256)):
//   newoff = dir*768 + (j>>5)*96 + (j&15)*6 + cls*2 + ((j>>4)&1)
__global__ __launch_bounds__(256, 2) void gemm_xg(
    const unsigned short* __restrict__ A,
    const unsigned short* __restrict__ W,
    const float* __restrict__ cbias,
    unsigned short* __restrict__ C)
{
  const int tid = threadIdx.x;
  const int l = tid & 63, wv = tid >> 6;
  const int col = l & 15, lq = l >> 4;
  const int n0 = blockIdx.x * 128;   // 12 n-tiles
  const int m0 = blockIdx.y * 128;   // 256 m-tiles
  const int wm = wv >> 1, wn = wv & 1;
  __shared__ char As[16384];   // [128 rows][64 k] bf16, 16B-slot XOR swizzle
  __shared__ char Ws[16384];

  f32x4 acc[4][4];
  #pragma unroll
  for (int a = 0; a < 4; a++)
    #pragma unroll
    for (int b2 = 0; b2 < 4; b2++) acc[a][b2] = (f32x4){0.f,0.f,0.f,0.f};

  short8 pa[4], pw[4];
  #pragma unroll
  for (int p = 0; p < 4; p++){
    const int qq = p*256 + tid, row = qq >> 3, sl = qq & 7;
    pa[p] = *(const short8*)(A + (m0+row)*512 + sl*8);
    pw[p] = *(const short8*)(W + (n0+row)*512 + sl*8);
  }

  for (int ko = 0; ko < 8; ++ko){
    __syncthreads();
    #pragma unroll
    for (int p = 0; p < 4; p++){
      const int qq = p*256 + tid, row = qq >> 3, sl = qq & 7;
      *(short8*)(As + row*128 + ((sl ^ (row & 7)) << 4)) = pa[p];
      *(short8*)(Ws + row*128 + ((sl ^ (row & 7)) << 4)) = pw[p];
    }
    __syncthreads();
    if (ko < 7){
      #pragma unroll
      for (int p = 0; p < 4; p++){
        const int qq = p*256 + tid, row = qq >> 3, sl = qq & 7;
        pa[p] = *(const short8*)(A + (m0+row)*512 + (ko+1)*64 + sl*8);
        pw[p] = *(const short8*)(W + (n0+row)*512 + (ko+1)*64 + sl*8);
      }
    }
    #pragma unroll
    for (int kt = 0; kt < 2; kt++){
      short8 af[4], bfr[4];
      #pragma unroll
      for (int mi = 0; mi < 4; mi++){
        const int r = wm*64 + mi*16 + col;
        af[mi] = *(const short8*)(As + r*128 + ((((kt<<2)|lq) ^ (r & 7)) << 4));
      }
      #pragma unroll
      for (int ni = 0; ni < 4; ni++){
        const int r = wn*64 + ni*16 + col;
        bfr[ni] = *(const short8*)(Ws + r*128 + ((((kt<<2)|lq) ^ (r & 7)) << 4));
      }
      #pragma unroll
      for (int mi = 0; mi < 4; mi++)
        #pragma unroll
        for (int ni = 0; ni < 4; ni++)
          acc[mi][ni] = __builtin_amdgcn_mfma_f32_16x16x32_bf16(af[mi], bfr[ni], acc[mi][ni], 0, 0, 0);
    }
  }
  // epilogue: C[m][perm(n)] = bf16(acc + cbias[n])
  #pragma unroll
  for (int ni = 0; ni < 4; ni++){
    const int n = n0 + wn*64 + ni*16 + col;
    const int dirn = (n >= 768) ? 1 : 0;
    const int g = n - dirn*768;
    const int cls = g >> 8;
    const int j = g & 255;
    const int noff = dirn*768 + (j >> 5)*96 + (j & 15)*6 + cls*2 + ((j >> 4) & 1);
    const float cb = cbias[n];
    #pragma unroll
    for (int mi = 0; mi < 4; mi++){
      const int m = m0 + wm*64 + mi*16 + lq*4;
      #pragma unroll
      for (int rg = 0; rg < 4; rg++)
        C[(m + rg)*1536 + noff] = f2bf(acc[mi][ni][rg] + cb);
    }
  }
}

// ---------------- GRU recurrence (v8: ONE recurrence per block, 128 blocks) ----------------
// grid = 128 blocks: blockIdx.x = dir*64 + batch. 512 threads (8 waves).
// Same 48-tile MFMA structure as before (wave w: r:{2w,2w+1} z:{16+2w,+1} n:{32+2w,+1}),
// but A has ONE valid row (row 0 = this batch): A-frags predicated on col==0, C/D row 0
// lives in lanes lq==0 reg 0 -> gate phase is 2 outputs on 16 lanes (~300 cy vs ~2400).
// MFMA floor per CU unchanged; gate/VALU phase parallelized across 128 CUs.
// LDS padded >80KB to force 1 block/CU (2 blocks would share the matrix pipe).
#define GRU_STEP(HB_R, HB_W, PF_CUR, PF_NXT, TCUR, TNEXT) do {                  \
  { const unsigned int* pp = (const unsigned int*)(xg + xgo + (TNEXT)*1536);    \
    PF_NXT[0] = pp[0]; PF_NXT[1] = pp[1]; PF_NXT[2] = pp[2]; }                  \
  f32x4 acc[6];                                                                 \
  _Pragma("unroll")                                                             \
  for (int i = 0; i < 6; i++) acc[i] = (f32x4){0.f,0.f,0.f,0.f};                \
  _Pragma("unroll")                                                             \
  for (int kt = 0; kt < 8; kt++){                                               \
    short8 a = {0,0,0,0,0,0,0,0};                                               \
    if (col == 0) a = *(const short8*)((HB_R) + kt*64 + lq*16);                 \
    _Pragma("unroll")                                                           \
    for (int i = 0; i < 5; i++)                                                 \
      acc[i] = __builtin_amdgcn_mfma_f32_16x16x32_bf16(a, bw[i][kt], acc[i], 0, 0, 0); \
    const short8 w5 = *(const short8*)(wlds + w*10240 + kt*1024 + l*16);        \
    acc[5] = __builtin_amdgcn_mfma_f32_16x16x32_bf16(a, w5, acc[5], 0, 0, 0);   \
  }                                                                             \
  if (lq == 0){                                                                 \
    _Pragma("unroll")                                                           \
    for (int c = 0; c < 2; c++){                                                \
      const float xr = bfu(PF_CUR[0], c);                                       \
      const float xz = bfu(PF_CUR[1], c);                                       \
      const float xn = bfu(PF_CUR[2], c);                                       \
      const float r_ = frcp(1.f + exp2a(-(xr + acc[c][0])));                    \
      const float z_ = frcp(1.f + exp2a(-(xz + acc[2+c][0])));                  \
      const float tt = xn + r_*(acc[4+c][0] + bhn[c]);                          \
      const float n_ = 1.f - 2.f*frcp(1.f + exp2a(tt));                         \
      const float h0 = hreg[c];                                                 \
      const float hn2 = n_ + z_*(h0 - n_);                                      \
      hreg[c] = hn2;                                                            \
      const unsigned short hb = f2bf(hn2);                                      \
      outb[obo + (TCUR)*512 + c*16] = hb;                                       \
      *(unsigned short*)((HB_W) + (32*w + c*16 + col)*2) = hb;                  \
    }                                                                           \
  }                                                                             \
  __syncthreads();                                                              \
} while(0)

__global__ __launch_bounds__(512, 2) void gru_rec(
    const unsigned short* __restrict__ xg,  // [64][512][1536] bf16, gate-permuted rows (prescaled)
    const unsigned short* __restrict__ whhL,// [2][768][256] bf16 (this layer, row-scaled)
    const float* __restrict__ bhhL,         // [2][768] (this layer, raw)
    unsigned short* __restrict__ outb)      // [64][512][512] bf16, logical h layout
{
  const int tid = threadIdx.x;
  const int l = tid & 63, w = tid >> 6;       // 8 waves
  const int col = l & 15, lq = l >> 4;
  const int dir = blockIdx.x >> 6, bg = blockIdx.x & 63;

  __shared__ char hbuf0[512];      // h bf16 [256], double-buffered
  __shared__ char hbuf1[512];
  __shared__ char wlds[8*10240];   // per-wave 6th tile (8KB used of 10KB stride) -> LDS >80KB: 1 block/CU

  const unsigned short* whh_d = whhL + dir*768*256;

  // weight fragments: B-frag lane holds W[g = nt*16 + col][k = kt*32 + lq*8 .. +8]
  short8 bw[5][8];
  #pragma unroll
  for (int i = 0; i < 6; i++){
    const int nt = (i < 2) ? (2*w + i) : (i < 4) ? (16 + 2*w + (i-2)) : (32 + 2*w + (i-4));
    const int g = nt*16 + col;
    #pragma unroll
    for (int kt = 0; kt < 8; kt++){
      short8 v = *(const short8*)(whh_d + g*256 + kt*32 + lq*8);
      if (i < 5) bw[i][kt] = v;
      else *(short8*)(wlds + w*10240 + kt*1024 + l*16) = v;
    }
  }

  float bhn[2];
  bhn[0] = bhhL[dir*768 + 512 + 32*w + col] * (2.f*L2E);
  bhn[1] = bhhL[dir*768 + 512 + 32*w + 16 + col] * (2.f*L2E);

  if (tid < 128){
    ((unsigned int*)hbuf0)[tid] = 0u;
    ((unsigned int*)hbuf1)[tid] = 0u;
  }

  float hreg[2] = {0.f, 0.f};

  const int xgo = bg*(512*1536) + dir*768 + (w*16 + col)*6;
  const int obo = bg*(512*512) + dir*256 + 32*w + col;

  // prologue: prefetch step 0 (all lanes load same addr per (w,col) — broadcast, harmless)
  unsigned int pfA[3], pfB[3];
  const int t0 = dir ? 511 : 0;
  const int dstep = dir ? -1 : 1;
  {
    const unsigned int* pp = (const unsigned int*)(xg + xgo + t0*1536);
    pfA[0] = pp[0]; pfA[1] = pp[1]; pfA[2] = pp[2];
  }

  __syncthreads();

  int tc = t0;
  #pragma unroll 1
  for (int ss = 0; ss < 256; ss++){
    const int tA = tc;
    const int tB = tA + dstep;
    const int tC = (ss == 255) ? tB : (tB + dstep);
    GRU_STEP(hbuf0, hbuf1, pfA, pfB, tA, tB);
    GRU_STEP(hbuf1, hbuf0, pfB, pfA, tB, tC);
    tc = tC;
  }
}

// ---------------- residual + LayerNorm + raw attention score ----------------
// grid = B*N blocks of 64 threads (1 wave). blockIdx.x = b*512 + t.
__global__ void ln_score(
    const unsigned short* __restrict__ h2b, const float* __restrict__ x,
    const int* __restrict__ nnode,
    const float* __restrict__ gam, const float* __restrict__ bet,
    const float* __restrict__ watt,
    float* __restrict__ hln, float* __restrict__ scores)
{
  const int bidx = blockIdx.x;
  const int b = bidx >> 9, n = bidx & 511;
  const int l = threadIdx.x;
  const int base = bidx*512;
  const int i0 = l*8;
  const bool valid = n < nnode[b];

  const short8 hv = *(const short8*)(h2b + base + i0);
  float y[8];
  #pragma unroll
  for (int p = 0; p < 2; p++){
    float4 xv = (float4){0.f,0.f,0.f,0.f};
    if (valid) xv = *(const float4*)(x + base + i0 + p*4);
    y[p*4+0] = bf2f((unsigned short)hv[p*4+0]) + xv.x;
    y[p*4+1] = bf2f((unsigned short)hv[p*4+1]) + xv.y;
    y[p*4+2] = bf2f((unsigned short)hv[p*4+2]) + xv.z;
    y[p*4+3] = bf2f((unsigned short)hv[p*4+3]) + xv.w;
  }
  float s = 0.f, sq = 0.f;
  #pragma unroll
  for (int i = 0; i < 8; i++){ s += y[i]; sq += y[i]*y[i]; }
  s = wredsum(s); sq = wredsum(sq);
  const float mu = s * (1.f/512.f);
  const float rstd = rsqrtf(sq * (1.f/512.f) - mu*mu + 1e-5f);

  float dot = 0.f;
  #pragma unroll
  for (int p = 0; p < 2; p++){
    const float4 gv = *(const float4*)(gam + i0 + p*4);
    const float4 bv = *(const float4*)(bet + i0 + p*4);
    const float4 wv = *(const float4*)(watt + i0 + p*4);
    float4 o;
    o.x = (y[p*4+0] - mu)*rstd*gv.x + bv.x;
    o.y = (y[p*4+1] - mu)*rstd*gv.y + bv.y;
    o.z = (y[p*4+2] - mu)*rstd*gv.z + bv.z;
    o.w = (y[p*4+3] - mu)*rstd*gv.w + bv.w;
    dot += o.x*wv.x + o.y*wv.y + o.z*wv.z + o.w*wv.w;
    *(float4*)(hln + base + i0 + p*4) = o;
  }
  dot = wredsum(dot);
  if (l == 0) scores[bidx] = dot;
}

// ---------------- softmax + weighted pooling ----------------
// grid = 64 blocks (one per batch), 256 threads.
__global__ void attn_pool(
    const float* __restrict__ hln, const float* __restrict__ scores,
    const float* __restrict__ watt, const float* __restrict__ q,
    float* __restrict__ out)
{
  __shared__ float sc[512];
  __shared__ float red[12];
  const int tid = threadIdx.x, l = tid & 63, w = tid >> 6;
  const int b = blockIdx.x;

  float p = q[b*512 + tid]*watt[512 + tid] + q[b*512 + 256 + tid]*watt[768 + tid];
  p = wredsum(p);
  if (l == 0) red[w] = p;
  __syncthreads();
  const float qd = red[0] + red[1] + red[2] + red[3];

  float s0 = scores[b*512 + tid] + qd;        s0 = s0 > 0.f ? s0 : 0.01f*s0;
  float s1 = scores[b*512 + 256 + tid] + qd;  s1 = s1 > 0.f ? s1 : 0.01f*s1;
  float m_ = wredmax(fmaxf(s0, s1));
  if (l == 0) red[4 + w] = m_;
  __syncthreads();
  const float mx = fmaxf(fmaxf(red[4], red[5]), fmaxf(red[6], red[7]));
  const float e0 = __expf(s0 - mx), e1 = __expf(s1 - mx);
  sc[tid] = e0; sc[tid + 256] = e1;
  float ss = wredsum(e0 + e1);
  if (l == 0) red[8 + w] = ss;
  __syncthreads();
  const float rden = 1.f / (red[8] + red[9] + red[10] + red[11]);

  const int h0 = tid*2;
  float a0 = 0.f, a1 = 0.f;
  for (int t = 0; t < 512; t++){
    const float wv = sc[t];
    const float2 v = *(const float2*)(hln + (b*512 + t)*512 + h0);
    a0 += v.x*wv; a1 += v.y*wv;
  }
  out[b*512 + h0]     = a0 * rden;
  out[b*512 + h0 + 1] = a1 * rden;
}

// ---------------- launcher ----------------
extern "C" void kernel_launch(void* const* d_in, const int* in_sizes, int n_in,
                              void* d_out, int out_size, void* d_ws, size_t ws_size,
                              hipStream_t stream)
{
  (void)in_sizes; (void)n_in; (void)out_size; (void)ws_size;
  const float* x    = (const float*)d_in[0];
  const int*   nn   = (const int*)d_in[1];
  const float* wih  = (const float*)d_in[2];
  const float* whh  = (const float*)d_in[3];
  const float* bih  = (const float*)d_in[4];
  const float* bhh  = (const float*)d_in[5];
  const float* lg   = (const float*)d_in[6];
  const float* lb   = (const float*)d_in[7];
  const float* watt = (const float*)d_in[8];
  const float* q    = (const float*)d_in[9];
  float* out = (float*)d_out;

  // workspace layout (total ~197 MiB)
  char* ws = (char*)d_ws;
  unsigned short* xg_b = (unsigned short*)(ws + 0);           // 100663296 B  [64][512][1536] bf16 (gate-permuted)
  unsigned short* xp_b = (unsigned short*)(ws + 100663296);   // 33554432 B
  unsigned short* h1_b = (unsigned short*)(ws + 134217728);   // 33554432 B
  unsigned short* h2_b = (unsigned short*)(ws + 167772160);   // 33554432 B
  unsigned short* wihb = (unsigned short*)(ws + 201326592);   // 3145728 B
  unsigned short* whhb = (unsigned short*)(ws + 204472320);   // 1572864 B
  float*         cbias = (float*)(ws + 206045184);            // 12288 B
  float*        scores = (float*)(ws + 206057472);            // 131072 B
  float*           hln = (float*)(ws + 0);                    // 67108864 B, reuses xg region

  prep_w<<<dim3(1024), dim3(256), 0, stream>>>(wih, whh, bih, bhh, wihb, whhb, cbias);
  prep_x<<<dim3(2048), dim3(256), 0, stream>>>(x, nn, xp_b);

  // layer 0
  gemm_xg<<<dim3(12, 256), dim3(256), 0, stream>>>(xp_b, wihb, cbias, xg_b);
  gru_rec<<<dim3(128), dim3(512), 0, stream>>>(xg_b, whhb, bhh, h1_b);

  // layer 1
  gemm_xg<<<dim3(12, 256), dim3(256), 0, stream>>>(h1_b, wihb + 1536*512, cbias + 1536, xg_b);
  gru_rec<<<dim3(128), dim3(512), 0, stream>>>(xg_b, whhb + 2*768*256, bhh + 1536, h2_b);

  ln_score<<<dim3(64*512), dim3(64), 0, stream>>>(h2_b, x, nn, lg, lb, watt, hln, scores);
  attn_pool<<<dim3(64), dim3(256), 0, stream>>>(hln, scores, watt, q, out);
}

// Round 11
// 1382.236 us; speedup vs baseline: 2.3560x; 1.1213x over previous
//
#include <hip/hip_runtime.h>
#include <stdint.h>

typedef __attribute__((ext_vector_type(8))) short short8;
typedef __attribute__((ext_vector_type(4))) float f32x4;

#define DEV static __device__ __forceinline__

#define L2E 1.4426950408889634f

// ---------------- helpers ----------------
DEV unsigned short f2bf(float f){
  unsigned int u = __float_as_uint(f);
  u = (u + 0x7FFFu + ((u >> 16) & 1u)) >> 16;
  return (unsigned short)u;
}
DEV float bf2f(unsigned short u){
  return __uint_as_float(((unsigned int)u) << 16);
}
DEV float frcp(float x){ return __builtin_amdgcn_rcpf(x); }
// raw v_exp_f32 (2^x). Proven identical to exp2f on-chip (R5 == R6 bitwise).
DEV float exp2a(float x){ float r; asm("v_exp_f32 %0, %1" : "=v"(r) : "v"(x)); return r; }
// unpack bf16 half c (0=lo,1=hi) of a dword to float
DEV float bfu(unsigned int u, int c){
  return c ? __uint_as_float(u & 0xFFFF0000u) : __uint_as_float(u << 16);
}
DEV float wredsum(float v){
  #pragma unroll
  for (int m = 32; m; m >>= 1) v += __shfl_xor(v, m);
  return v;
}
DEV float wredmax(float v){
  #pragma unroll
  for (int m = 32; m; m >>= 1) v = fmaxf(v, __shfl_xor(v, m));
  return v;
}

// dims
#define BB 64
#define NN 512
#define HH 512
#define HC 256

// ---------------- prep: weights -> bf16 (rows scaled by L2E / 2*L2E), combined bias ----------------
__global__ void prep_w(const float* __restrict__ wih, const float* __restrict__ whh,
                       const float* __restrict__ bih, const float* __restrict__ bhh,
                       unsigned short* __restrict__ wihb, unsigned short* __restrict__ whhb,
                       float* __restrict__ cbias)
{
  const int NW1 = 2*2*768*512;   // 1572864
  const int NW2 = 2*2*768*256;   // 786432
  const int NCB = 2*1536;        // 3072
  for (int i = blockIdx.x*256 + threadIdx.x; i < NW1+NW2+NCB; i += gridDim.x*256){
    if (i < NW1){
      const int row = (i >> 9) % 768;       // true mod-768
      const float sc = ((row >> 8) == 2) ? 2.f*L2E : L2E;
      wihb[i] = f2bf(wih[i] * sc);
    } else if (i < NW1+NW2){
      const int k = i - NW1;
      const int row = (k >> 8) % 768;       // true mod-768
      const float sc = ((row >> 8) == 2) ? 2.f*L2E : L2E;
      whhb[k] = f2bf(whh[k] * sc);
    } else {
      int k = i - NW1 - NW2;
      int L = k / 1536, r = k % 1536;
      int dd = r / 768, g = r % 768;
      int idx = (L*2 + dd)*768 + g;
      const float sc = (g >= 512) ? 2.f*L2E : L2E;
      // fold b_ih always; fold b_hh for r,z gates. b_hh[n] stays in recurrence.
      cbias[k] = (bih[idx] + (g < 512 ? bhh[idx] : 0.f)) * sc;
    }
  }
}

// ---------------- prep: mask x -> bf16 copy ----------------
__global__ void prep_x(const float* __restrict__ x, const int* __restrict__ nnode,
                       unsigned short* __restrict__ xpb)
{
  const int TOT4 = (BB*NN*HH) >> 2;  // 4194304
  for (int i = blockIdx.x*256 + threadIdx.x; i < TOT4; i += gridDim.x*256){
    const int e = i << 2;
    const int b = e >> 18;          // /(512*512)
    const int n = (e >> 9) & 511;
    float4 v = *(const float4*)(x + e);
    if (n >= nnode[b]) { v.x = 0.f; v.y = 0.f; v.z = 0.f; v.w = 0.f; }
    ushort4 o;
    o.x = f2bf(v.x); o.y = f2bf(v.y); o.z = f2bf(v.z); o.w = f2bf(v.w);
    *(ushort4*)(xpb + e) = o;
  }
}

// ---------------- input-gate GEMM: C[32768][1536] = A[32768][512] * W[1536][512]^T + cbias ----------------
// Output row layout is GATE-PERMUTED for gru_rec:
//   for n = dir*768 + g, g = cls*256 + j (cls=r/z/n, j = hidden idx in [0,256)):
//   newoff = dir*768 + (j>>5)*96 + (j&15)*6 + cls*2 + ((j>>4)&1)
__global__ __launch_bounds__(256, 2) void gemm_xg(
    const unsigned short* __restrict__ A,
    const unsigned short* __restrict__ W,
    const float* __restrict__ cbias,
    unsigned short* __restrict__ C)
{
  const int tid = threadIdx.x;
  const int l = tid & 63, wv = tid >> 6;
  const int col = l & 15, lq = l >> 4;
  const int n0 = blockIdx.x * 128;   // 12 n-tiles
  const int m0 = blockIdx.y * 128;   // 256 m-tiles
  const int wm = wv >> 1, wn = wv & 1;
  __shared__ char As[16384];   // [128 rows][64 k] bf16, 16B-slot XOR swizzle
  __shared__ char Ws[16384];

  f32x4 acc[4][4];
  #pragma unroll
  for (int a = 0; a < 4; a++)
    #pragma unroll
    for (int b2 = 0; b2 < 4; b2++) acc[a][b2] = (f32x4){0.f,0.f,0.f,0.f};

  short8 pa[4], pw[4];
  #pragma unroll
  for (int p = 0; p < 4; p++){
    const int qq = p*256 + tid, row = qq >> 3, sl = qq & 7;
    pa[p] = *(const short8*)(A + (m0+row)*512 + sl*8);
    pw[p] = *(const short8*)(W + (n0+row)*512 + sl*8);
  }

  for (int ko = 0; ko < 8; ++ko){
    __syncthreads();
    #pragma unroll
    for (int p = 0; p < 4; p++){
      const int qq = p*256 + tid, row = qq >> 3, sl = qq & 7;
      *(short8*)(As + row*128 + ((sl ^ (row & 7)) << 4)) = pa[p];
      *(short8*)(Ws + row*128 + ((sl ^ (row & 7)) << 4)) = pw[p];
    }
    __syncthreads();
    if (ko < 7){
      #pragma unroll
      for (int p = 0; p < 4; p++){
        const int qq = p*256 + tid, row = qq >> 3, sl = qq & 7;
        pa[p] = *(const short8*)(A + (m0+row)*512 + (ko+1)*64 + sl*8);
        pw[p] = *(const short8*)(W + (n0+row)*512 + (ko+1)*64 + sl*8);
      }
    }
    #pragma unroll
    for (int kt = 0; kt < 2; kt++){
      short8 af[4], bfr[4];
      #pragma unroll
      for (int mi = 0; mi < 4; mi++){
        const int r = wm*64 + mi*16 + col;
        af[mi] = *(const short8*)(As + r*128 + ((((kt<<2)|lq) ^ (r & 7)) << 4));
      }
      #pragma unroll
      for (int ni = 0; ni < 4; ni++){
        const int r = wn*64 + ni*16 + col;
        bfr[ni] = *(const short8*)(Ws + r*128 + ((((kt<<2)|lq) ^ (r & 7)) << 4));
      }
      #pragma unroll
      for (int mi = 0; mi < 4; mi++)
        #pragma unroll
        for (int ni = 0; ni < 4; ni++)
          acc[mi][ni] = __builtin_amdgcn_mfma_f32_16x16x32_bf16(af[mi], bfr[ni], acc[mi][ni], 0, 0, 0);
    }
  }
  // epilogue: C[m][perm(n)] = bf16(acc + cbias[n])
  #pragma unroll
  for (int ni = 0; ni < 4; ni++){
    const int n = n0 + wn*64 + ni*16 + col;
    const int dirn = (n >= 768) ? 1 : 0;
    const int g = n - dirn*768;
    const int cls = g >> 8;
    const int j = g & 255;
    const int noff = dirn*768 + (j >> 5)*96 + (j & 15)*6 + cls*2 + ((j >> 4) & 1);
    const float cb = cbias[n];
    #pragma unroll
    for (int mi = 0; mi < 4; mi++){
      const int m = m0 + wm*64 + mi*16 + lq*4;
      #pragma unroll
      for (int rg = 0; rg < 4; rg++)
        C[(m + rg)*1536 + noff] = f2bf(acc[mi][ni][rg] + cb);
    }
  }
}

// ---------------- GRU recurrence (v9: broadcast-A, one recurrence per block) ----------------
// grid = 128 blocks: blockIdx.x = dir*64 + batch. 512 threads (8 waves).
// Wave w gate-tiles: r:{2w,2w+1} z:{16+2w,+1} n:{32+2w,+1}. A has ONE meaningful row:
// instead of predicating (zero-fill + exec juggling cost ~200 VALU cy/step), ALL lanes
// load the SAME h fragment (per-lq broadcast, conflict-free): every A row = h, so all
// C rows are equal and row 0 (lq==0, reg 0) is exactly the real batch row. Garbage-free,
// branch-free inner loop.
// 5 weight tiles in VGPRs, 6th in per-wave LDS. hbuf double-buffered (1 barrier/step).
// xg prefetched one step ahead (load-bearing, R8 ablation: removing it = +1240 idle cy).
// LDS padded >80KB to force 1 block/CU (2 blocks would share the matrix pipe).
#define GRU_STEP(HB_R, HB_W, PF_CUR, PF_NXT, TCUR, TNEXT) do {                  \
  { const uint3 v3 = *(const uint3*)(xg + xgo + (TNEXT)*1536);                  \
    PF_NXT[0] = v3.x; PF_NXT[1] = v3.y; PF_NXT[2] = v3.z; }                     \
  f32x4 acc[6];                                                                 \
  _Pragma("unroll")                                                             \
  for (int i = 0; i < 6; i++) acc[i] = (f32x4){0.f,0.f,0.f,0.f};                \
  _Pragma("unroll")                                                             \
  for (int kt = 0; kt < 8; kt++){                                               \
    const short8 a = *(const short8*)((HB_R) + kt*64 + lq*16);                  \
    _Pragma("unroll")                                                           \
    for (int i = 0; i < 5; i++)                                                 \
      acc[i] = __builtin_amdgcn_mfma_f32_16x16x32_bf16(a, bw[i][kt], acc[i], 0, 0, 0); \
    const short8 w5 = *(const short8*)(wlds + w*10240 + kt*1024 + l*16);        \
    acc[5] = __builtin_amdgcn_mfma_f32_16x16x32_bf16(a, w5, acc[5], 0, 0, 0);   \
  }                                                                             \
  if (lq == 0){                                                                 \
    _Pragma("unroll")                                                           \
    for (int c = 0; c < 2; c++){                                                \
      const float xr = bfu(PF_CUR[0], c);                                       \
      const float xz = bfu(PF_CUR[1], c);                                       \
      const float xn = bfu(PF_CUR[2], c);                                       \
      const float r_ = frcp(1.f + exp2a(-(xr + acc[c][0])));                    \
      const float z_ = frcp(1.f + exp2a(-(xz + acc[2+c][0])));                  \
      const float tt = xn + r_*(acc[4+c][0] + bhn[c]);                          \
      const float n_ = 1.f - 2.f*frcp(1.f + exp2a(tt));                         \
      const float h0 = hreg[c];                                                 \
      const float hn2 = n_ + z_*(h0 - n_);                                      \
      hreg[c] = hn2;                                                            \
      const unsigned short hb = f2bf(hn2);                                      \
      outb[obo + (TCUR)*512 + c*16] = hb;                                       \
      *(unsigned short*)((HB_W) + (32*w + c*16 + col)*2) = hb;                  \
    }                                                                           \
  }                                                                             \
  __syncthreads();                                                              \
} while(0)

__global__ __launch_bounds__(512, 2) void gru_rec(
    const unsigned short* __restrict__ xg,  // [64][512][1536] bf16, gate-permuted rows (prescaled)
    const unsigned short* __restrict__ whhL,// [2][768][256] bf16 (this layer, row-scaled)
    const float* __restrict__ bhhL,         // [2][768] (this layer, raw)
    unsigned short* __restrict__ outb)      // [64][512][512] bf16, logical h layout
{
  const int tid = threadIdx.x;
  const int l = tid & 63, w = tid >> 6;       // 8 waves
  const int col = l & 15, lq = l >> 4;
  const int dir = blockIdx.x >> 6, bg = blockIdx.x & 63;

  __shared__ char hbuf0[512];      // h bf16 [256], double-buffered
  __shared__ char hbuf1[512];
  __shared__ char wlds[8*10240];   // per-wave 6th tile (8KB used of 10KB stride) -> LDS >80KB: 1 block/CU

  const unsigned short* whh_d = whhL + dir*768*256;

  // weight fragments: B-frag lane holds W[g = nt*16 + col][k = kt*32 + lq*8 .. +8]
  short8 bw[5][8];
  #pragma unroll
  for (int i = 0; i < 6; i++){
    const int nt = (i < 2) ? (2*w + i) : (i < 4) ? (16 + 2*w + (i-2)) : (32 + 2*w + (i-4));
    const int g = nt*16 + col;
    #pragma unroll
    for (int kt = 0; kt < 8; kt++){
      short8 v = *(const short8*)(whh_d + g*256 + kt*32 + lq*8);
      if (i < 5) bw[i][kt] = v;
      else *(short8*)(wlds + w*10240 + kt*1024 + l*16) = v;
    }
  }

  float bhn[2];
  bhn[0] = bhhL[dir*768 + 512 + 32*w + col] * (2.f*L2E);
  bhn[1] = bhhL[dir*768 + 512 + 32*w + 16 + col] * (2.f*L2E);

  if (tid < 128){
    ((unsigned int*)hbuf0)[tid] = 0u;
    ((unsigned int*)hbuf1)[tid] = 0u;
  }

  float hreg[2] = {0.f, 0.f};

  const int xgo = bg*(512*1536) + dir*768 + (w*16 + col)*6;
  const int obo = bg*(512*512) + dir*256 + 32*w + col;

  // prologue: prefetch step 0
  unsigned int pfA[3], pfB[3];
  const int t0 = dir ? 511 : 0;
  const int dstep = dir ? -1 : 1;
  {
    const uint3 v3 = *(const uint3*)(xg + xgo + t0*1536);
    pfA[0] = v3.x; pfA[1] = v3.y; pfA[2] = v3.z;
  }

  __syncthreads();

  int tc = t0;
  #pragma unroll 1
  for (int ss = 0; ss < 256; ss++){
    const int tA = tc;
    const int tB = tA + dstep;
    const int tC = (ss == 255) ? tB : (tB + dstep);
    GRU_STEP(hbuf0, hbuf1, pfA, pfB, tA, tB);
    GRU_STEP(hbuf1, hbuf0, pfB, pfA, tB, tC);
    tc = tC;
  }
}

// ---------------- residual + LayerNorm + raw attention score ----------------
// grid = B*N blocks of 64 threads (1 wave). blockIdx.x = b*512 + t.
__global__ void ln_score(
    const unsigned short* __restrict__ h2b, const float* __restrict__ x,
    const int* __restrict__ nnode,
    const float* __restrict__ gam, const float* __restrict__ bet,
    const float* __restrict__ watt,
    float* __restrict__ hln, float* __restrict__ scores)
{
  const int bidx = blockIdx.x;
  const int b = bidx >> 9, n = bidx & 511;
  const int l = threadIdx.x;
  const int base = bidx*512;
  const int i0 = l*8;
  const bool valid = n < nnode[b];

  const short8 hv = *(const short8*)(h2b + base + i0);
  float y[8];
  #pragma unroll
  for (int p = 0; p < 2; p++){
    float4 xv = (float4){0.f,0.f,0.f,0.f};
    if (valid) xv = *(const float4*)(x + base + i0 + p*4);
    y[p*4+0] = bf2f((unsigned short)hv[p*4+0]) + xv.x;
    y[p*4+1] = bf2f((unsigned short)hv[p*4+1]) + xv.y;
    y[p*4+2] = bf2f((unsigned short)hv[p*4+2]) + xv.z;
    y[p*4+3] = bf2f((unsigned short)hv[p*4+3]) + xv.w;
  }
  float s = 0.f, sq = 0.f;
  #pragma unroll
  for (int i = 0; i < 8; i++){ s += y[i]; sq += y[i]*y[i]; }
  s = wredsum(s); sq = wredsum(sq);
  const float mu = s * (1.f/512.f);
  const float rstd = rsqrtf(sq * (1.f/512.f) - mu*mu + 1e-5f);

  float dot = 0.f;
  #pragma unroll
  for (int p = 0; p < 2; p++){
    const float4 gv = *(const float4*)(gam + i0 + p*4);
    const float4 bv = *(const float4*)(bet + i0 + p*4);
    const float4 wv = *(const float4*)(watt + i0 + p*4);
    float4 o;
    o.x = (y[p*4+0] - mu)*rstd*gv.x + bv.x;
    o.y = (y[p*4+1] - mu)*rstd*gv.y + bv.y;
    o.z = (y[p*4+2] - mu)*rstd*gv.z + bv.z;
    o.w = (y[p*4+3] - mu)*rstd*gv.w + bv.w;
    dot += o.x*wv.x + o.y*wv.y + o.z*wv.z + o.w*wv.w;
    *(float4*)(hln + base + i0 + p*4) = o;
  }
  dot = wredsum(dot);
  if (l == 0) scores[bidx] = dot;
}

// ---------------- softmax + weighted pooling ----------------
// grid = 64 blocks (one per batch), 256 threads.
__global__ void attn_pool(
    const float* __restrict__ hln, const float* __restrict__ scores,
    const float* __restrict__ watt, const float* __restrict__ q,
    float* __restrict__ out)
{
  __shared__ float sc[512];
  __shared__ float red[12];
  const int tid = threadIdx.x, l = tid & 63, w = tid >> 6;
  const int b = blockIdx.x;

  float p = q[b*512 + tid]*watt[512 + tid] + q[b*512 + 256 + tid]*watt[768 + tid];
  p = wredsum(p);
  if (l == 0) red[w] = p;
  __syncthreads();
  const float qd = red[0] + red[1] + red[2] + red[3];

  float s0 = scores[b*512 + tid] + qd;        s0 = s0 > 0.f ? s0 : 0.01f*s0;
  float s1 = scores[b*512 + 256 + tid] + qd;  s1 = s1 > 0.f ? s1 : 0.01f*s1;
  float m_ = wredmax(fmaxf(s0, s1));
  if (l == 0) red[4 + w] = m_;
  __syncthreads();
  const float mx = fmaxf(fmaxf(red[4], red[5]), fmaxf(red[6], red[7]));
  const float e0 = __expf(s0 - mx), e1 = __expf(s1 - mx);
  sc[tid] = e0; sc[tid + 256] = e1;
  float ss = wredsum(e0 + e1);
  if (l == 0) red[8 + w] = ss;
  __syncthreads();
  const float rden = 1.f / (red[8] + red[9] + red[10] + red[11]);

  const int h0 = tid*2;
  float a0 = 0.f, a1 = 0.f;
  for (int t = 0; t < 512; t++){
    const float wv = sc[t];
    const float2 v = *(const float2*)(hln + (b*512 + t)*512 + h0);
    a0 += v.x*wv; a1 += v.y*wv;
  }
  out[b*512 + h0]     = a0 * rden;
  out[b*512 + h0 + 1] = a1 * rden;
}

// ---------------- launcher ----------------
extern "C" void kernel_launch(void* const* d_in, const int* in_sizes, int n_in,
                              void* d_out, int out_size, void* d_ws, size_t ws_size,
                              hipStream_t stream)
{
  (void)in_sizes; (void)n_in; (void)out_size; (void)ws_size;
  const float* x    = (const float*)d_in[0];
  const int*   nn   = (const int*)d_in[1];
  const float* wih  = (const float*)d_in[2];
  const float* whh  = (const float*)d_in[3];
  const float* bih  = (const float*)d_in[4];
  const float* bhh  = (const float*)d_in[5];
  const float* lg   = (const float*)d_in[6];
  const float* lb   = (const float*)d_in[7];
  const float* watt = (const float*)d_in[8];
  const float* q    = (const float*)d_in[9];
  float* out = (float*)d_out;

  // workspace layout (total ~197 MiB)
  char* ws = (char*)d_ws;
  unsigned short* xg_b = (unsigned short*)(ws + 0);           // 100663296 B  [64][512][1536] bf16 (gate-permuted)
  unsigned short* xp_b = (unsigned short*)(ws + 100663296);   // 33554432 B
  unsigned short* h1_b = (unsigned short*)(ws + 134217728);   // 33554432 B
  unsigned short* h2_b = (unsigned short*)(ws + 167772160);   // 33554432 B
  unsigned short* wihb = (unsigned short*)(ws + 201326592);   // 3145728 B
  unsigned short* whhb = (unsigned short*)(ws + 204472320);   // 1572864 B
  float*         cbias = (float*)(ws + 206045184);            // 12288 B
  float*        scores = (float*)(ws + 206057472);            // 131072 B
  float*           hln = (float*)(ws + 0);                    // 67108864 B, reuses xg region

  prep_w<<<dim3(1024), dim3(256), 0, stream>>>(wih, whh, bih, bhh, wihb, whhb, cbias);
  prep_x<<<dim3(2048), dim3(256), 0, stream>>>(x, nn, xp_b);

  // layer 0
  gemm_xg<<<dim3(12, 256), dim3(256), 0, stream>>>(xp_b, wihb, cbias, xg_b);
  gru_rec<<<dim3(128), dim3(512), 0, stream>>>(xg_b, whhb, bhh, h1_b);

  // layer 1
  gemm_xg<<<dim3(12, 256), dim3(256), 0, stream>>>(h1_b, wihb + 1536*512, cbias + 1536, xg_b);
  gru_rec<<<dim3(128), dim3(512), 0, stream>>>(xg_b, whhb + 2*768*256, bhh + 1536, h2_b);

  ln_score<<<dim3(64*512), dim3(64), 0, stream>>>(h2_b, x, nn, lg, lb, watt, hln, scores);
  attn_pool<<<dim3(64), dim3(256), 0, stream>>>(hln, scores, watt, q, out);
}